// Round 3
// baseline (88.630 us; speedup 1.0000x reference)
//
#include <hip/hip_runtime.h>

// Problem constants: pred [1,4,2048,2048] fp32, true [2048,2048] int32 (labels 0..3)
static constexpr int HW   = 2048 * 2048;   // pixels
static constexpr int NQ   = HW / 4;        // float4 / int4 quads
static constexpr int NBLK = 2048;
static constexpr int NTHR = 256;
static constexpr int QPT  = NQ / (NBLK * NTHR);  // = 2 quads (8 pixels) per thread

// d_ws layout:
//   [0]      u32 ticket counter (memset to 0 by kernel_launch each call)
//   [64..]   uint4 partial[NBLK][3]  -- 12 u32 per block:
//            [0..3] p_sum, [4..7] t_sum, [8..11] inter (per class)
static constexpr size_t PART_OFF = 64;  // bytes

__global__ __launch_bounds__(NTHR) void count_kernel(const float* __restrict__ pred,
                                                     const int* __restrict__ lbl,
                                                     unsigned int* __restrict__ ws,
                                                     float* __restrict__ out) {
    const float4* __restrict__ p0 = (const float4*)(pred);
    const float4* __restrict__ p1 = (const float4*)(pred + (size_t)HW);
    const float4* __restrict__ p2 = (const float4*)(pred + (size_t)2 * HW);
    const float4* __restrict__ p3 = (const float4*)(pred + (size_t)3 * HW);
    const int4*   __restrict__ tl = (const int4*)(lbl);
    uint4* __restrict__ partial = (uint4*)((char*)ws + PART_OFF);

    // byte-packed per-thread counters: 8-bit lane per class (max 8 pixels/thread)
    unsigned int pc = 0u, tc = 0u, ic = 0u;

    const int base = blockIdx.x * NTHR + threadIdx.x;
#pragma unroll
    for (int q = 0; q < QPT; ++q) {
        const int i = base + q * (NBLK * NTHR);
        float4 a = p0[i];
        float4 b = p1[i];
        float4 c = p2[i];
        float4 d = p3[i];
        int4   t = tl[i];

        float a_[4] = {a.x, a.y, a.z, a.w};
        float b_[4] = {b.x, b.y, b.z, b.w};
        float c_[4] = {c.x, c.y, c.z, c.w};
        float d_[4] = {d.x, d.y, d.z, d.w};
        int   t_[4] = {t.x, t.y, t.z, t.w};

#pragma unroll
        for (int j = 0; j < 4; ++j) {
            // jnp.argmax tie-break: first (lowest) index among maxima -> strict '>'
            float best = a_[j];
            int   pi   = 0;
            if (b_[j] > best) { best = b_[j]; pi = 1; }
            if (c_[j] > best) { best = c_[j]; pi = 2; }
            if (d_[j] > best) { best = d_[j]; pi = 3; }
            int tj = t_[j];
            pc += 1u << (pi * 8);
            tc += 1u << (tj * 8);
            ic += (pi == tj) ? (1u << (pi * 8)) : 0u;
        }
    }

    // widen 8-bit lanes -> two u32 with 16-bit lanes (classes {0,2} in lo, {1,3} in hi)
    unsigned int plo = pc & 0x00FF00FFu, phi = (pc >> 8) & 0x00FF00FFu;
    unsigned int tlo = tc & 0x00FF00FFu, thi = (tc >> 8) & 0x00FF00FFu;
    unsigned int ilo = ic & 0x00FF00FFu, ihi = (ic >> 8) & 0x00FF00FFu;

    // wave-64 reduction (16-bit lanes: max 64*8=512 per lane, no overflow)
#pragma unroll
    for (int off = 32; off > 0; off >>= 1) {
        plo += __shfl_down(plo, off);
        phi += __shfl_down(phi, off);
        tlo += __shfl_down(tlo, off);
        thi += __shfl_down(thi, off);
        ilo += __shfl_down(ilo, off);
        ihi += __shfl_down(ihi, off);
    }

    __shared__ unsigned int red[NTHR / 64][6];
    __shared__ int last_flag;
    int wave = threadIdx.x >> 6;
    int lane = threadIdx.x & 63;
    if (lane == 0) {
        red[wave][0] = plo; red[wave][1] = phi;
        red[wave][2] = tlo; red[wave][3] = thi;
        red[wave][4] = ilo; red[wave][5] = ihi;
    }
    __syncthreads();

    if (threadIdx.x == 0) {
        unsigned int s[6];
#pragma unroll
        for (int k = 0; k < 6; ++k) {
            unsigned int acc = 0;
#pragma unroll
            for (int w = 0; w < NTHR / 64; ++w) acc += red[w][k];
            s[k] = acc;  // 16-bit lanes: max 4*512 = 2048, no overflow
        }
        // unpack into row of 12: p0..p3, t0..t3, i0..i3
        uint4 r0 = make_uint4(s[0] & 0xFFFFu, s[1] & 0xFFFFu, s[0] >> 16, s[1] >> 16);
        uint4 r1 = make_uint4(s[2] & 0xFFFFu, s[3] & 0xFFFFu, s[2] >> 16, s[3] >> 16);
        uint4 r2 = make_uint4(s[4] & 0xFFFFu, s[5] & 0xFFFFu, s[4] >> 16, s[5] >> 16);
        uint4* row = partial + (size_t)blockIdx.x * 3;
        row[0] = r0; row[1] = r1; row[2] = r2;
        __threadfence();  // release: make partials visible device-wide
        unsigned int ticket = atomicAdd(ws, 1u);
        last_flag = (ticket == (unsigned int)(NBLK - 1)) ? 1 : 0;
    }
    __syncthreads();
    if (!last_flag) return;

    // ---- last block: reduce all partials + scalar epilogue ----
    __threadfence();  // acquire: invalidate stale cached partials

    unsigned int s[12];
#pragma unroll
    for (int k = 0; k < 12; ++k) s[k] = 0u;

    for (int b = threadIdx.x; b < NBLK; b += NTHR) {
        const uint4* row = partial + (size_t)b * 3;
        uint4 r0 = row[0], r1 = row[1], r2 = row[2];
        s[0] += r0.x; s[1] += r0.y; s[2]  += r0.z; s[3]  += r0.w;
        s[4] += r1.x; s[5] += r1.y; s[6]  += r1.z; s[7]  += r1.w;
        s[8] += r2.x; s[9] += r2.y; s[10] += r2.z; s[11] += r2.w;
    }

#pragma unroll
    for (int off = 32; off > 0; off >>= 1) {
#pragma unroll
        for (int k = 0; k < 12; ++k) s[k] += __shfl_down(s[k], off);
    }

    __shared__ unsigned int red2[NTHR / 64][12];
    if (lane == 0) {
#pragma unroll
        for (int k = 0; k < 12; ++k) red2[wave][k] = s[k];
    }
    __syncthreads();

    if (threadIdx.x == 0) {
        unsigned int tot[12];
#pragma unroll
        for (int k = 0; k < 12; ++k) {
            unsigned int acc = 0;
#pragma unroll
            for (int w = 0; w < NTHR / 64; ++w) acc += red2[w][k];
            tot[k] = acc;
        }
        float p[4], t[4], in[4];
        float sp = 0.f, st = 0.f;
#pragma unroll
        for (int c = 0; c < 4; ++c) {
            p[c]  = (float)tot[c];
            t[c]  = (float)tot[4 + c];
            in[c] = (float)tot[8 + c];
            sp += p[c];
            st += t[c];
        }
        const float S = 1e-5f;
        float total = sp + st;  // == p1h.sum() + t1h.sum()
        float dsum = 0.f, isum = 0.f;
        int npres = 0;
#pragma unroll
        for (int c = 0; c < 4; ++c) {
            if (tot[4 + c] > 0u) {  // class present in `true`
                ++npres;
                dsum += 1.0f - (2.0f * in[c] + S) / (p[c] + t[c] + S);
                isum += 1.0f - (in[c] + S) / (total + S - in[c]);
            }
        }
        float n = (float)(npres > 0 ? npres : 1);
        out[0] = dsum / n + isum / n;
    }
}

extern "C" void kernel_launch(void* const* d_in, const int* in_sizes, int n_in,
                              void* d_out, int out_size, void* d_ws, size_t ws_size,
                              hipStream_t stream) {
    const float* pred = (const float*)d_in[0];
    const int*   lbl  = (const int*)d_in[1];
    float*       out  = (float*)d_out;
    unsigned int* ws  = (unsigned int*)d_ws;

    // zero the ticket counter (4 bytes) -- graph-capture-safe async memset
    hipMemsetAsync(ws, 0, sizeof(unsigned int), stream);
    count_kernel<<<NBLK, NTHR, 0, stream>>>(pred, lbl, ws, out);
}

// Round 4
// 25.509 us; speedup vs baseline: 3.4744x; 3.4744x over previous
//
#include <hip/hip_runtime.h>

// Problem constants: pred [1,4,2048,2048] fp32, true [2048,2048] int32 (labels 0..3)
static constexpr int HW   = 2048 * 2048;   // pixels
static constexpr int NQ   = HW / 4;        // float4 / int4 quads
static constexpr int NBLK = 2048;
static constexpr int NTHR = 256;
static constexpr int QPT  = NQ / (NBLK * NTHR);  // = 2 quads (8 pixels) per thread

// d_ws layout: uint4 partial[NBLK][3]  (12 u32 per block)
//  [0..3] p_sum per class (argmax==c), [4..7] t_sum, [8..11] inter

__global__ __launch_bounds__(NTHR) void count_kernel(const float* __restrict__ pred,
                                                     const int* __restrict__ lbl,
                                                     uint4* __restrict__ partial) {
    const float4* __restrict__ p0 = (const float4*)(pred);
    const float4* __restrict__ p1 = (const float4*)(pred + (size_t)HW);
    const float4* __restrict__ p2 = (const float4*)(pred + (size_t)2 * HW);
    const float4* __restrict__ p3 = (const float4*)(pred + (size_t)3 * HW);
    const int4*   __restrict__ tl = (const int4*)(lbl);

    const int base = blockIdx.x * NTHR + threadIdx.x;

    // ---- load phase: issue all 10 independent 16B loads back-to-back ----
    float4 va[QPT], vb[QPT], vc[QPT], vd[QPT];
    int4   vt[QPT];
#pragma unroll
    for (int q = 0; q < QPT; ++q) {
        const int i = base + q * (NBLK * NTHR);
        va[q] = p0[i];
        vb[q] = p1[i];
        vc[q] = p2[i];
        vd[q] = p3[i];
        vt[q] = tl[i];
    }

    // ---- compute phase ----
    // byte-packed per-thread counters: 8-bit lane per class (max 8 pixels/thread)
    unsigned int pc = 0u, tc = 0u, ic = 0u;
#pragma unroll
    for (int q = 0; q < QPT; ++q) {
        float a_[4] = {va[q].x, va[q].y, va[q].z, va[q].w};
        float b_[4] = {vb[q].x, vb[q].y, vb[q].z, vb[q].w};
        float c_[4] = {vc[q].x, vc[q].y, vc[q].z, vc[q].w};
        float d_[4] = {vd[q].x, vd[q].y, vd[q].z, vd[q].w};
        int   t_[4] = {vt[q].x, vt[q].y, vt[q].z, vt[q].w};
#pragma unroll
        for (int j = 0; j < 4; ++j) {
            // jnp.argmax tie-break: first (lowest) index among maxima -> strict '>'
            float best = a_[j];
            int   pi   = 0;
            if (b_[j] > best) { best = b_[j]; pi = 1; }
            if (c_[j] > best) { best = c_[j]; pi = 2; }
            if (d_[j] > best) { best = d_[j]; pi = 3; }
            int tj = t_[j];
            pc += 1u << (pi * 8);
            tc += 1u << (tj * 8);
            ic += (pi == tj) ? (1u << (pi * 8)) : 0u;
        }
    }

    // widen 8-bit lanes -> two u32 with 16-bit lanes (classes {0,2} in lo, {1,3} in hi)
    unsigned int plo = pc & 0x00FF00FFu, phi = (pc >> 8) & 0x00FF00FFu;
    unsigned int tlo = tc & 0x00FF00FFu, thi = (tc >> 8) & 0x00FF00FFu;
    unsigned int ilo = ic & 0x00FF00FFu, ihi = (ic >> 8) & 0x00FF00FFu;

    // wave-64 reduction (16-bit lanes: max 64*8=512 per lane, no overflow)
#pragma unroll
    for (int off = 32; off > 0; off >>= 1) {
        plo += __shfl_down(plo, off);
        phi += __shfl_down(phi, off);
        tlo += __shfl_down(tlo, off);
        thi += __shfl_down(thi, off);
        ilo += __shfl_down(ilo, off);
        ihi += __shfl_down(ihi, off);
    }

    __shared__ unsigned int red[NTHR / 64][6];
    int wave = threadIdx.x >> 6;
    int lane = threadIdx.x & 63;
    if (lane == 0) {
        red[wave][0] = plo; red[wave][1] = phi;
        red[wave][2] = tlo; red[wave][3] = thi;
        red[wave][4] = ilo; red[wave][5] = ihi;
    }
    __syncthreads();

    if (threadIdx.x == 0) {
        unsigned int s[6];
#pragma unroll
        for (int k = 0; k < 6; ++k) {
            unsigned int acc = 0;
#pragma unroll
            for (int w = 0; w < NTHR / 64; ++w) acc += red[w][k];
            s[k] = acc;  // 16-bit lanes: max 4*512 = 2048, no overflow
        }
        uint4* row = partial + (size_t)blockIdx.x * 3;
        // lo16 = class{0 or 1}, hi16 = class{2 or 3}
        row[0] = make_uint4(s[0] & 0xFFFFu, s[1] & 0xFFFFu, s[0] >> 16, s[1] >> 16);  // p
        row[1] = make_uint4(s[2] & 0xFFFFu, s[3] & 0xFFFFu, s[2] >> 16, s[3] >> 16);  // t
        row[2] = make_uint4(s[4] & 0xFFFFu, s[5] & 0xFFFFu, s[4] >> 16, s[5] >> 16);  // i
    }
}

__global__ __launch_bounds__(NTHR) void finalize_kernel(const uint4* __restrict__ partial,
                                                        float* __restrict__ out) {
    unsigned int s[12];
#pragma unroll
    for (int k = 0; k < 12; ++k) s[k] = 0u;

    for (int b = threadIdx.x; b < NBLK; b += NTHR) {
        const uint4* row = partial + (size_t)b * 3;
        uint4 r0 = row[0], r1 = row[1], r2 = row[2];
        s[0] += r0.x; s[1] += r0.y; s[2]  += r0.z; s[3]  += r0.w;
        s[4] += r1.x; s[5] += r1.y; s[6]  += r1.z; s[7]  += r1.w;
        s[8] += r2.x; s[9] += r2.y; s[10] += r2.z; s[11] += r2.w;
    }

    // wave reduce each of the 12 sums
#pragma unroll
    for (int off = 32; off > 0; off >>= 1) {
#pragma unroll
        for (int k = 0; k < 12; ++k) s[k] += __shfl_down(s[k], off);
    }

    __shared__ unsigned int red[NTHR / 64][12];
    int wave = threadIdx.x >> 6;
    int lane = threadIdx.x & 63;
    if (lane == 0) {
#pragma unroll
        for (int k = 0; k < 12; ++k) red[wave][k] = s[k];
    }
    __syncthreads();

    if (threadIdx.x == 0) {
        unsigned int tot[12];
#pragma unroll
        for (int k = 0; k < 12; ++k) {
            unsigned int acc = 0;
#pragma unroll
            for (int w = 0; w < NTHR / 64; ++w) acc += red[w][k];
            tot[k] = acc;
        }
        float p[4], t[4], in[4];
        float sp = 0.f, st = 0.f;
#pragma unroll
        for (int c = 0; c < 4; ++c) {
            p[c]  = (float)tot[c];
            t[c]  = (float)tot[4 + c];
            in[c] = (float)tot[8 + c];
            sp += p[c];
            st += t[c];
        }
        const float S = 1e-5f;
        float total = sp + st;  // == p1h.sum() + t1h.sum()
        float dsum = 0.f, isum = 0.f;
        int npres = 0;
#pragma unroll
        for (int c = 0; c < 4; ++c) {
            if (tot[4 + c] > 0u) {  // class present in `true`
                ++npres;
                dsum += 1.0f - (2.0f * in[c] + S) / (p[c] + t[c] + S);
                isum += 1.0f - (in[c] + S) / (total + S - in[c]);
            }
        }
        float n = (float)(npres > 0 ? npres : 1);
        out[0] = dsum / n + isum / n;
    }
}

extern "C" void kernel_launch(void* const* d_in, const int* in_sizes, int n_in,
                              void* d_out, int out_size, void* d_ws, size_t ws_size,
                              hipStream_t stream) {
    const float* pred = (const float*)d_in[0];
    const int*   lbl  = (const int*)d_in[1];
    float*       out  = (float*)d_out;
    uint4*       partial = (uint4*)d_ws;   // NBLK * 3 uint4 = 96 KB

    count_kernel<<<NBLK, NTHR, 0, stream>>>(pred, lbl, partial);
    finalize_kernel<<<1, NTHR, 0, stream>>>(partial, out);
}